// Round 1
// baseline (368.973 us; speedup 1.0000x reference)
//
#include <hip/hip_runtime.h>
#include <math.h>

#define NQ 12
#define DIM 4096                 // 2^NQ
#define NLAYERS 4
#define NENC 4
#define BATCH 1024
#define THREADS 256
#define PER_THREAD (DIM / THREADS)           // 16
#define NPAIRS (DIM / 2)                     // 2048
#define PAIRS_PER_THREAD (NPAIRS / THREADS)  // 8

__device__ inline float2 cmul(float2 a, float2 b) {
    return make_float2(a.x * b.x - a.y * b.y, a.x * b.y + a.y * b.x);
}
__device__ inline float2 cadd(float2 a, float2 b) {
    return make_float2(a.x + b.x, a.y + b.y);
}

__global__ __launch_bounds__(THREADS)
void vqc_kernel(const float* __restrict__ features,
                const float* __restrict__ theta,
                const float* __restrict__ alpha,
                float* __restrict__ out)
{
    __shared__ float2 st[DIM];                   // 32 KB statevector
    __shared__ float2 enc[NQ][2];                // per-qubit encoding states
    __shared__ float  cs[NLAYERS * NQ * 3][2];   // cos/sin of theta/2
    __shared__ float2 um[NLAYERS * NQ][4];       // fused U = RZ*RY*RX per (l,q)
    __shared__ float  red[NQ * 4];               // cross-wave reduction

    const int tid = threadIdx.x;
    const int e = blockIdx.x & 3;       // encoder
    const int b = blockIdx.x >> 2;      // sample

    // ---- per-qubit encoding single-qubit states ----
    if (tid < NQ) {
        float f = features[b * NQ + tid];
        float s, c;
        sincosf(0.5f * f, &s, &c);
        const float r = 0.70710678118654752f;
        float2 a0, a1;
        if (e == 0)      { a0 = make_float2(c, 0.f);            a1 = make_float2(0.f, -s); }          // angle_rx: RX|0>
        else if (e == 1) { a0 = make_float2(c, 0.f);            a1 = make_float2(s, 0.f); }           // angle_ry: RY|0>
        else if (e == 2) { a0 = make_float2(c * r, -s * r);     a1 = a0; }                            // h_angle_rx: RX H|0>
        else             { a0 = make_float2((c - s) * r, 0.f);  a1 = make_float2((c + s) * r, 0.f); } // h_angle_ry: RY H|0>
        enc[tid][0] = a0; enc[tid][1] = a1;
    }
    // ---- sincos of all theta/2 (one thread per angle) ----
    if (tid < NLAYERS * NQ * 3) {
        float t = theta[tid];
        float s, c;
        sincosf(0.5f * t, &s, &c);
        cs[tid][0] = c; cs[tid][1] = s;
    }
    __syncthreads();

    // ---- fused gate matrices U = RZ(t2)*RY(t1)*RX(t0), one thread per (l,q) ----
    if (tid < NLAYERS * NQ) {
        float c0 = cs[tid * 3 + 0][0], s0 = cs[tid * 3 + 0][1];
        float c1 = cs[tid * 3 + 1][0], s1 = cs[tid * 3 + 1][1];
        float c2 = cs[tid * 3 + 2][0], s2 = cs[tid * 3 + 2][1];
        // A = RY*RX
        float2 a00 = make_float2( c1 * c0,  s1 * s0);
        float2 a01 = make_float2(-s1 * c0, -c1 * s0);
        float2 a10 = make_float2( s1 * c0, -c1 * s0);
        float2 a11 = make_float2( c1 * c0, -s1 * s0);
        float2 ep = make_float2(c2, -s2);   // e^{-i t2/2}
        float2 em = make_float2(c2,  s2);   // e^{+i t2/2}
        um[tid][0] = cmul(ep, a00);
        um[tid][1] = cmul(ep, a01);
        um[tid][2] = cmul(em, a10);
        um[tid][3] = cmul(em, a11);
    }

    // ---- build product state directly (encoding fully folded in) ----
    for (int j = 0; j < PER_THREAD; ++j) {
        int i = j * THREADS + tid;
        float2 amp = enc[0][(i >> 11) & 1];
        #pragma unroll
        for (int q = 1; q < NQ; ++q)
            amp = cmul(amp, enc[q][(i >> (11 - q)) & 1]);
        st[i] = amp;
    }
    __syncthreads();

    // ---- variational layers ----
    for (int l = 0; l < NLAYERS; ++l) {
        for (int q = 0; q < NQ; ++q) {
            const float2* U = um[l * NQ + q];
            float2 u00 = U[0], u01 = U[1], u10 = U[2], u11 = U[3];
            const int k = 11 - q;           // bit position of qubit q
            const int S = 1 << k;           // pair stride
            #pragma unroll
            for (int j = 0; j < PAIRS_PER_THREAD; ++j) {
                int p = j * THREADS + tid;
                int i0 = ((p >> k) << (k + 1)) | (p & (S - 1));
                int i1 = i0 | S;
                float2 x0 = st[i0], x1 = st[i1];
                float2 y0 = cadd(cmul(u00, x0), cmul(u01, x1));
                float2 y1 = cadd(cmul(u10, x0), cmul(u11, x1));
                st[i0] = y0;
                st[i1] = y1;
            }
            __syncthreads();
        }
        // CNOT ladders: each full ladder is one GF(2)-affine involution
        //  even layer (q=0,2,..,10): i ^= (i>>1) & 0x555
        //  odd  layer (q=1,3,..,9):  i ^= (i>>1) & 0x2AA
        #pragma unroll
        for (int pass = 0; pass < 2; ++pass) {
            const int TM = (pass == 0) ? 0x555 : 0x2AA;
            for (int j = 0; j < PER_THREAD; ++j) {
                int i = j * THREADS + tid;
                int ip = i ^ ((i >> 1) & TM);
                if (ip > i) {   // each unordered pair handled by exactly one thread
                    float2 t0 = st[i];
                    st[i] = st[ip];
                    st[ip] = t0;
                }
            }
            __syncthreads();
        }
    }

    // ---- measurement: <Z_q> for all 12 qubits ----
    float ez[NQ];
    #pragma unroll
    for (int q = 0; q < NQ; ++q) ez[q] = 0.f;
    for (int j = 0; j < PER_THREAD; ++j) {
        int i = j * THREADS + tid;
        float2 a = st[i];
        float p = a.x * a.x + a.y * a.y;
        #pragma unroll
        for (int q = 0; q < NQ; ++q)
            ez[q] += ((i >> (11 - q)) & 1) ? -p : p;
    }
    const int lane = tid & 63;
    const int wv = tid >> 6;
    #pragma unroll
    for (int q = 0; q < NQ; ++q) {
        float v = ez[q];
        #pragma unroll
        for (int m = 32; m >= 1; m >>= 1) v += __shfl_xor(v, m, 64);
        if (lane == 0) red[q * 4 + wv] = v;
    }
    __syncthreads();

    if (tid < NQ) {
        float a0 = alpha[0], a1 = alpha[1], a2 = alpha[2], a3 = alpha[3];
        float mx = fmaxf(fmaxf(a0, a1), fmaxf(a2, a3));
        float e0 = expf(a0 - mx), e1 = expf(a1 - mx), e2 = expf(a2 - mx), e3 = expf(a3 - mx);
        float den = e0 + e1 + e2 + e3;
        float w = ((e == 0) ? e0 : (e == 1) ? e1 : (e == 2) ? e2 : e3) / den;
        float v = red[tid * 4 + 0] + red[tid * 4 + 1] + red[tid * 4 + 2] + red[tid * 4 + 3];
        atomicAdd(out + b * NQ + tid, w * v);
    }
}

extern "C" void kernel_launch(void* const* d_in, const int* in_sizes, int n_in,
                              void* d_out, int out_size, void* d_ws, size_t ws_size,
                              hipStream_t stream) {
    const float* features = (const float*)d_in[0];
    const float* theta    = (const float*)d_in[1];
    const float* alpha    = (const float*)d_in[2];
    float* out = (float*)d_out;

    hipMemsetAsync(out, 0, (size_t)out_size * sizeof(float), stream);
    vqc_kernel<<<dim3(BATCH * NENC), THREADS, 0, stream>>>(features, theta, alpha, out);
}

// Round 2
// 159.907 us; speedup vs baseline: 2.3074x; 2.3074x over previous
//
#include <hip/hip_runtime.h>
#include <math.h>

#define NQ 12
#define DIM 4096
#define NL 4
#define THREADS 256
#define SWZ(e) ((e) ^ (((e) >> 3) & 14))

__device__ inline float2 cmul(float2 a, float2 b) {
    return make_float2(fmaf(a.x, b.x, -a.y * b.y), fmaf(a.x, b.y, a.y * b.x));
}
__device__ inline float2 cfma(float2 a, float2 b, float2 c) {   // a*b + c
    return make_float2(fmaf(a.x, b.x, fmaf(-a.y, b.y, c.x)),
                       fmaf(a.x, b.y, fmaf(a.y, b.x, c.y)));
}

__global__ __launch_bounds__(THREADS, 4)
void vqc_kernel(const float* __restrict__ features,
                const float* __restrict__ theta,
                const float* __restrict__ alpha,
                float* __restrict__ out)
{
    __shared__ float2 st[DIM];                 // 32 KB statevector (swizzled layout)
    __shared__ float2 cs[NL * NQ * 3];         // (cos, sin) of theta/2
    __shared__ float2 U48[NL * NQ][4];         // fused RZ*RY*RX per (l,q)
    __shared__ float2 enc[NQ][2];
    __shared__ float2 pairT[6][4];             // enc[2p] (x) enc[2p+1]
    __shared__ float  red[12 * 4];
    __shared__ float  wez[12];

    const int tid = threadIdx.x;
    const bool special = (blockIdx.x == 0);    // shared h_angle_rx circuit, runs first
    int b = 0, eslot = 0;
    if (!special) { int bid = blockIdx.x - 1; eslot = bid % 3; b = bid / 3; }

    // ---- stage 1: theta sincos (tid<144) + per-qubit encoding states (tid 192..203) ----
    if (tid < NL * NQ * 3) {
        float t = theta[tid];
        float s, c; sincosf(0.5f * t, &s, &c);
        cs[tid] = make_float2(c, s);
    }
    {
        int t2 = tid - 192;
        if (t2 >= 0 && t2 < NQ) {
            const float r = 0.70710678118654752f;
            float2 a0, a1;
            if (special) {                      // |+> per qubit (global phase dropped)
                a0 = make_float2(r, 0.f); a1 = a0;
            } else {
                float f = features[b * NQ + t2];
                float s, c; sincosf(0.5f * f, &s, &c);
                if (eslot == 0)      { a0 = make_float2(c, 0.f); a1 = make_float2(0.f, -s); }          // angle_rx
                else if (eslot == 1) { a0 = make_float2(c, 0.f); a1 = make_float2(s, 0.f); }           // angle_ry
                else                 { a0 = make_float2((c - s) * r, 0.f); a1 = make_float2((c + s) * r, 0.f); } // h_angle_ry
            }
            enc[t2][0] = a0; enc[t2][1] = a1;
        }
    }
    __syncthreads();

    // ---- stage 2: fused per-qubit U (tid<48) + pair tables (tid 64..87) ----
    if (tid < NL * NQ) {
        float c0 = cs[tid*3+0].x, s0 = cs[tid*3+0].y;
        float c1 = cs[tid*3+1].x, s1 = cs[tid*3+1].y;
        float c2 = cs[tid*3+2].x, s2 = cs[tid*3+2].y;
        float2 a00 = make_float2( c1*c0,  s1*s0);
        float2 a01 = make_float2(-s1*c0, -c1*s0);
        float2 a10 = make_float2( s1*c0, -c1*s0);
        float2 a11 = make_float2( c1*c0, -s1*s0);
        float2 ep = make_float2(c2, -s2), em = make_float2(c2, s2);
        U48[tid][0] = cmul(ep, a00); U48[tid][1] = cmul(ep, a01);
        U48[tid][2] = cmul(em, a10); U48[tid][3] = cmul(em, a11);
    }
    {
        int t3 = tid - 64;
        if (t3 >= 0 && t3 < 24) {
            int p = t3 >> 2, v = t3 & 3;
            pairT[p][v] = cmul(enc[2*p][v >> 1], enc[2*p + 1][v & 1]);
        }
    }
    __syncthreads();

    // ---- product state build (prefix-shared, 2 cmul/amp) ----
    #pragma unroll
    for (int h = 0; h < 4; ++h) {
        int G = h * 256 + tid;                 // i >> 2
        float2 pre = cmul(cmul(pairT[0][(G>>8)&3], pairT[1][(G>>6)&3]),
                          cmul(pairT[2][(G>>4)&3], pairT[3][(G>>2)&3]));
        pre = cmul(pre, pairT[4][G & 3]);
        #pragma unroll
        for (int c = 0; c < 4; ++c) {
            int i = G * 4 + c;
            st[SWZ(i)] = cmul(pre, pairT[5][c]);
        }
    }
    __syncthreads();

    // ---- variational layers: 6 fused 4x4 passes/layer; even CNOTs baked in,
    //      odd-CNOT ladder folded into addressing parity (amask) ----
    for (int l = 0; l < NL; ++l) {
        const int amask = (l & 1) ? 0x2AA : 0;
        #pragma unroll
        for (int m = 0; m < 6; ++m) {
            const int k = 10 - 2 * m;          // low bit of pair (qubits 2m,2m+1)
            const float2 lo00 = U48[l*NQ + 2*m+1][0], lo01 = U48[l*NQ + 2*m+1][1],
                         lo10 = U48[l*NQ + 2*m+1][2], lo11 = U48[l*NQ + 2*m+1][3];
            const float2 hi00 = U48[l*NQ + 2*m  ][0], hi01 = U48[l*NQ + 2*m  ][1],
                         hi10 = U48[l*NQ + 2*m  ][2], hi11 = U48[l*NQ + 2*m  ][3];
            // parity contribution of the member-offset low bit (only for k>=2)
            const int pt  = (k >= 2) ? ((1 << (k - 1)) & amask) : 0;
            const int spt = SWZ(pt);
            #pragma unroll 2
            for (int j = 0; j < 4; ++j) {
                int g  = j * 256 + tid;                                // logical group
                int ib = ((g >> k) << (k + 2)) | (g & ((1 << k) - 1)); // logical base
                int e0 = ib ^ ((ib >> 1) & amask);                     // parity map
                int A0 = SWZ(e0);
                int ad0 = A0;
                int ad1 = A0 ^ (SWZ(1 << k) ^ spt);
                int ad2 = A0 ^  SWZ(2 << k);
                int ad3 = A0 ^ (SWZ(3 << k) ^ spt);
                float2 x0 = st[ad0], x1 = st[ad1], x2 = st[ad2], x3 = st[ad3];
                // lo-qubit stage
                float2 z0 = cfma(lo00, x0, cmul(lo01, x1));
                float2 z1 = cfma(lo10, x0, cmul(lo11, x1));
                float2 z2 = cfma(lo00, x2, cmul(lo01, x3));
                float2 z3 = cfma(lo10, x2, cmul(lo11, x3));
                // hi-qubit stage
                float2 y0 = cfma(hi00, z0, cmul(hi01, z2));
                float2 y1 = cfma(hi00, z1, cmul(hi01, z3));
                float2 y2 = cfma(hi10, z0, cmul(hi11, z2));
                float2 y3 = cfma(hi10, z1, cmul(hi11, z3));
                // even CNOT: out[2] = pre[3], out[3] = pre[2]
                st[ad0] = y0; st[ad1] = y1;
                st[ad2] = y3; st[ad3] = y2;
            }
            __syncthreads();
        }
    }

    // ---- measurement (parity is identity after 4 layers) ----
    float ez0 = 0.f, ez1 = 0.f, ez2 = 0.f, ez3 = 0.f, psum = 0.f;
    #pragma unroll
    for (int j = 0; j < 16; ++j) {
        int i = j * 256 + tid;
        float2 am = st[SWZ(i)];
        float p = fmaf(am.x, am.x, am.y * am.y);
        ez0 += (j & 8) ? -p : p;
        ez1 += (j & 4) ? -p : p;
        ez2 += (j & 2) ? -p : p;
        ez3 += (j & 1) ? -p : p;
        psum += p;
    }
    float vals[12];
    vals[0] = ez0; vals[1] = ez1; vals[2] = ez2; vals[3] = ez3;
    #pragma unroll
    for (int q = 4; q < 12; ++q)
        vals[q] = ((tid >> (11 - q)) & 1) ? -psum : psum;

    const int lane = tid & 63, wv = tid >> 6;
    #pragma unroll
    for (int q = 0; q < 12; ++q) {
        float v = vals[q];
        #pragma unroll
        for (int mm = 32; mm >= 1; mm >>= 1) v += __shfl_xor(v, mm, 64);
        if (lane == 0) red[q * 4 + wv] = v;
    }
    __syncthreads();

    if (tid < 12) {
        float A0 = alpha[0], A1 = alpha[1], A2 = alpha[2], A3 = alpha[3];
        float mx = fmaxf(fmaxf(A0, A1), fmaxf(A2, A3));
        float E0 = expf(A0 - mx), E1 = expf(A1 - mx), E2 = expf(A2 - mx), E3 = expf(A3 - mx);
        float den = E0 + E1 + E2 + E3;
        float v = red[tid*4+0] + red[tid*4+1] + red[tid*4+2] + red[tid*4+3];
        if (special) {
            wez[tid] = (E2 / den) * v;
        } else {
            float w = ((eslot == 0) ? E0 : (eslot == 1) ? E1 : E3) / den;
            atomicAdd(out + b * NQ + tid, w * v);
        }
    }
    if (special) {
        __syncthreads();
        for (int bb = tid; bb < 1024; bb += THREADS) {
            #pragma unroll
            for (int q = 0; q < NQ; ++q)
                atomicAdd(out + bb * NQ + q, wez[q]);
        }
    }
}

extern "C" void kernel_launch(void* const* d_in, const int* in_sizes, int n_in,
                              void* d_out, int out_size, void* d_ws, size_t ws_size,
                              hipStream_t stream) {
    const float* features = (const float*)d_in[0];
    const float* theta    = (const float*)d_in[1];
    const float* alpha    = (const float*)d_in[2];
    float* out = (float*)d_out;

    hipMemsetAsync(out, 0, (size_t)out_size * sizeof(float), stream);
    vqc_kernel<<<dim3(3 * 1024 + 1), THREADS, 0, stream>>>(features, theta, alpha, out);
}

// Round 3
// 144.468 us; speedup vs baseline: 2.5540x; 1.1069x over previous
//
#include <hip/hip_runtime.h>
#include <math.h>

#define NQ 12
#define DIM 4096
#define NL 4
#define THREADS 256

typedef float v2f __attribute__((ext_vector_type(2)));

// bank swizzle: XOR-linear, bijective on [0,4096)
#define SWZC(e) ((e) ^ (((e) >> 3) & 14) ^ (((e) >> 7) & 15))

__device__ __forceinline__ v2f pkfma(v2f a, v2f b, v2f c) {
    v2f d; asm("v_pk_fma_f32 %0, %1, %2, %3" : "=v"(d) : "v"(a), "v"(b), "v"(c)); return d;
}
__device__ __forceinline__ v2f pkmul(v2f a, v2f b) {
    v2f d; asm("v_pk_mul_f32 %0, %1, %2" : "=v"(d) : "v"(a), "v"(b)); return d;
}
__device__ __forceinline__ v2f pkadd(v2f a, v2f b) {
    v2f d; asm("v_pk_add_f32 %0, %1, %2" : "=v"(d) : "v"(a), "v"(b)); return d;
}

__device__ __forceinline__ float2 cmulS(float2 a, float2 b) {
    return make_float2(fmaf(a.x, b.x, -a.y * b.y), fmaf(a.x, b.y, a.y * b.x));
}

struct C3 { v2f r, i, ni; };   // (re,re), (im,im), (-im,-im)

// out = K * x   (complex, packed over 2 circuits)
#define CMULP(orE, orI, K, xre, xim) \
    { orE = pkfma(K.ni, xim, pkmul(K.r, xre)); orI = pkfma(K.i, xre, pkmul(K.r, xim)); }
// out += K * x
#define CMACP(orE, orI, K, xre, xim) \
    { orE = pkfma(K.r, xre, pkfma(K.ni, xim, orE)); orI = pkfma(K.r, xim, pkfma(K.i, xre, orI)); }

// fused 4x4 pair-gate on quad (A,B,C,D) = (00,01,10,11) of (hi,lo) bits,
// lo-stage then hi-stage, with even-CNOT (swap outputs 2,3) baked in
#define QUADBODY(A_, B_, C_, D_) { \
    v2f z0r,z0i,z1r,z1i,z2r,z2i,z3r,z3i; \
    CMULP(z0r,z0i, l00, sre[A_], sim[A_]); CMACP(z0r,z0i, l01, sre[B_], sim[B_]); \
    CMULP(z1r,z1i, l10, sre[A_], sim[A_]); CMACP(z1r,z1i, l11, sre[B_], sim[B_]); \
    CMULP(z2r,z2i, l00, sre[C_], sim[C_]); CMACP(z2r,z2i, l01, sre[D_], sim[D_]); \
    CMULP(z3r,z3i, l10, sre[C_], sim[C_]); CMACP(z3r,z3i, l11, sre[D_], sim[D_]); \
    v2f y0r,y0i,y1r,y1i,y2r,y2i,y3r,y3i; \
    CMULP(y0r,y0i, h00, z0r,z0i); CMACP(y0r,y0i, h01, z2r,z2i); \
    CMULP(y1r,y1i, h00, z1r,z1i); CMACP(y1r,y1i, h01, z3r,z3i); \
    CMULP(y2r,y2i, h10, z0r,z0i); CMACP(y2r,y2i, h11, z2r,z2i); \
    CMULP(y3r,y3i, h10, z1r,z1i); CMACP(y3r,y3i, h11, z3r,z3i); \
    sre[A_]=y0r; sim[A_]=y0i; sre[B_]=y1r; sim[B_]=y1i; \
    sre[C_]=y3r; sim[C_]=y3i; sre[D_]=y2r; sim[D_]=y2i; }

#define LOADU \
    C3 l00={U[0][0],U[0][1],U[0][2]}, l01={U[1][0],U[1][1],U[1][2]}, \
       l10={U[2][0],U[2][1],U[2][2]}, l11={U[3][0],U[3][1],U[3][2]}, \
       h00={U[4][0],U[4][1],U[4][2]}, h01={U[5][0],U[5][1],U[5][2]}, \
       h10={U[6][0],U[6][1],U[6][2]}, h11={U[7][0],U[7][1],U[7][2]};

__device__ __forceinline__ void pass_hi(v2f* sre, v2f* sim, const v2f (*U)[3]) {
    LOADU
    QUADBODY(0,4,8,12) QUADBODY(1,5,9,13) QUADBODY(2,6,10,14) QUADBODY(3,7,11,15)
}
__device__ __forceinline__ void pass_lo(v2f* sre, v2f* sim, const v2f (*U)[3]) {
    LOADU
    QUADBODY(0,1,2,3) QUADBODY(4,5,6,7) QUADBODY(8,9,10,11) QUADBODY(12,13,14,15)
}

__global__ __launch_bounds__(THREADS, 2)
void vqc_kernel(const float* __restrict__ features,
                const float* __restrict__ theta,
                const float* __restrict__ alpha,
                float* __restrict__ out)
{
    __shared__ v2f re_p[DIM];                 // 32 KB: packed re-plane (2 circuits)
    __shared__ v2f im_p[DIM];                 // 32 KB
    __shared__ float2 cs[NL * NQ * 3];
    __shared__ float2 U48[NL * NQ][4];
    __shared__ v2f Upk[24][8][3];             // per (layer,pair): 8 coeffs x (re2,im2,nim2)
    __shared__ float2 enc[2][NQ][2];
    __shared__ float2 pairT[2][6][4];
    __shared__ float2 loc[2][16];
    __shared__ v2f red[12 * 4];
    __shared__ float wez[12];

    const int tid = threadIdx.x;
    const bool special = (blockIdx.x == 0);   // shared h_angle_rx circuit (|+>^12 up to phase)
    const int gA = special ? 0 : 2 * ((int)blockIdx.x - 1);
    const int gB = gA + 1;

    // ---- stage 1: theta sincos + encoding states (2 circuits) ----
    if (tid < NL * NQ * 3) {
        float s, c; sincosf(0.5f * theta[tid], &s, &c);
        cs[tid] = make_float2(c, s);
    }
    if (tid >= 160 && tid < 184) {
        int c_ = (tid - 160) / 12, q = (tid - 160) % 12;
        const float r_ = 0.70710678118654752f;
        float2 a0, a1;
        if (special) { a0 = make_float2(r_, 0.f); a1 = a0; }
        else {
            int g = c_ ? gB : gA;
            int esl = g % 3, b = g / 3;
            float f = features[b * NQ + q];
            float s, c; sincosf(0.5f * f, &s, &c);
            if (esl == 0)      { a0 = make_float2(c, 0.f); a1 = make_float2(0.f, -s); }          // angle_rx
            else if (esl == 1) { a0 = make_float2(c, 0.f); a1 = make_float2(s, 0.f); }           // angle_ry
            else               { a0 = make_float2((c-s)*r_, 0.f); a1 = make_float2((c+s)*r_, 0.f); } // h_angle_ry
        }
        enc[c_][q][0] = a0; enc[c_][q][1] = a1;
    }
    __syncthreads();

    // ---- stage 2: fused U = RZ*RY*RX (48 thr) + pair tables (48 thr) ----
    if (tid < NL * NQ) {
        float c0 = cs[tid*3+0].x, s0 = cs[tid*3+0].y;
        float c1 = cs[tid*3+1].x, s1 = cs[tid*3+1].y;
        float c2 = cs[tid*3+2].x, s2 = cs[tid*3+2].y;
        float2 a00 = make_float2( c1*c0,  s1*s0);
        float2 a01 = make_float2(-s1*c0, -c1*s0);
        float2 a10 = make_float2( s1*c0, -c1*s0);
        float2 a11 = make_float2( c1*c0, -s1*s0);
        float2 ep = make_float2(c2, -s2), em = make_float2(c2, s2);
        U48[tid][0] = cmulS(ep, a00); U48[tid][1] = cmulS(ep, a01);
        U48[tid][2] = cmulS(em, a10); U48[tid][3] = cmulS(em, a11);
    }
    if (tid >= 64 && tid < 112) {
        int x = tid - 64;
        int c_ = x / 24, y = x % 24, p = y >> 2, v = y & 3;
        pairT[c_][p][v] = cmulS(enc[c_][2*p][v >> 1], enc[c_][2*p + 1][v & 1]);
    }
    __syncthreads();

    // ---- stage 3: packed coeff triples (192 thr) + local product table (32 thr) ----
    if (tid < 192) {
        int p = tid >> 3, k = tid & 7;       // p = l*6+m
        int l = p / 6, m = p % 6;
        int q = (k < 4) ? (2*m + 1) : (2*m); // k<4: lo (qubit 2m+1), else hi (qubit 2m)
        float2 u = U48[l*NQ + q][k & 3];
        v2f r2 = {u.x, u.x}, i2 = {u.y, u.y}, n2 = {-u.y, -u.y};
        Upk[p][k][0] = r2; Upk[p][k][1] = i2; Upk[p][k][2] = n2;
    }
    if (tid >= 192 && tid < 224) {
        int x = tid - 192; int c_ = x >> 4, j = x & 15;
        loc[c_][j] = cmulS(pairT[c_][4][j >> 2], pairT[c_][5][j & 3]);
    }
    __syncthreads();

    // ---- build product state directly into LA registers (i = tid<<4 | j) ----
    v2f sre[16], sim[16];
    {
        int t = tid;
        float2 preA = cmulS(cmulS(pairT[0][0][(t>>6)&3], pairT[0][1][(t>>4)&3]),
                            cmulS(pairT[0][2][(t>>2)&3], pairT[0][3][t&3]));
        float2 preB = cmulS(cmulS(pairT[1][0][(t>>6)&3], pairT[1][1][(t>>4)&3]),
                            cmulS(pairT[1][2][(t>>2)&3], pairT[1][3][t&3]));
        #pragma unroll
        for (int j = 0; j < 16; ++j) {
            float2 aA = cmulS(preA, loc[0][j]);
            float2 aB = cmulS(preB, loc[1][j]);
            v2f r = {aA.x, aB.x}, i = {aA.y, aB.y};
            sre[j] = r; sim[j] = i;
        }
    }

    // ---- 4 variational layers ----
    #pragma unroll 1
    for (int l = 0; l < NL; ++l) {
        // LA: pairs P4 (bits 3,2), P5 (bits 1,0)
        pass_hi(sre, sim, Upk[l*6 + 4]);
        pass_lo(sre, sim, Upk[l*6 + 5]);
        // relayout LA -> LB
        {
            int ba = SWZC(tid << 4);
            #pragma unroll
            for (int j = 0; j < 16; ++j) { re_p[ba ^ j] = sre[j]; im_p[ba ^ j] = sim[j]; }
            __syncthreads();
            int ib = ((tid >> 4) << 8) | (tid & 15);
            int bb = SWZC(ib);
            #pragma unroll
            for (int j = 0; j < 16; ++j) { int a = bb ^ SWZC(j << 4); sre[j] = re_p[a]; sim[j] = im_p[a]; }
            __syncthreads();
        }
        // LB: pairs P2 (bits 7,6), P3 (bits 5,4)
        pass_hi(sre, sim, Upk[l*6 + 2]);
        pass_lo(sre, sim, Upk[l*6 + 3]);
        // relayout LB -> LC
        {
            int ib = ((tid >> 4) << 8) | (tid & 15);
            int bb = SWZC(ib);
            #pragma unroll
            for (int j = 0; j < 16; ++j) { int a = bb ^ SWZC(j << 4); re_p[a] = sre[j]; im_p[a] = sim[j]; }
            __syncthreads();
            int bc = SWZC(tid);
            #pragma unroll
            for (int j = 0; j < 16; ++j) { int a = bc ^ SWZC(j << 8); sre[j] = re_p[a]; sim[j] = im_p[a]; }
            __syncthreads();
        }
        // LC: pairs P0 (bits 11,10), P1 (bits 9,8)
        pass_hi(sre, sim, Upk[l*6 + 0]);
        pass_lo(sre, sim, Upk[l*6 + 1]);
        if (l < NL - 1) {
            // relayout LC -> LA applying odd-CNOT ladder sigma: new[i] = old[sigma(i)]
            int bc = SWZC(tid);
            #pragma unroll
            for (int j = 0; j < 16; ++j) { int a = bc ^ SWZC(j << 8); re_p[a] = sre[j]; im_p[a] = sim[j]; }
            __syncthreads();
            int t = tid;
            int sx = (t << 4) ^ ((t & 1) << 3) ^ (((t >> 2) & 1) << 5)
                             ^ (((t >> 4) & 1) << 7) ^ (((t >> 6) & 1) << 9);  // sigma(t<<4)
            int bs = SWZC(sx);
            #pragma unroll
            for (int j = 0; j < 16; ++j) {
                int sj = j ^ ((j >> 1) & 2);   // sigma on low nibble; SWZC(sj)=sj
                sre[j] = re_p[bs ^ sj]; sim[j] = im_p[bs ^ sj];
            }
            __syncthreads();
        }
    }

    // ---- measurement in LC, layer-3 sigma folded into sign indices ----
    // register (t,j) holds amp for true index m = sigma((j<<8)|t)
    v2f s0 = {0.f,0.f}, s1 = {0.f,0.f}, s2 = {0.f,0.f}, s3 = {0.f,0.f}, psum = {0.f,0.f};
    {
        const v2f MONE = {-1.f, -1.f};
        #pragma unroll
        for (int j = 0; j < 16; ++j) {
            v2f p = pkfma(sim[j], sim[j], pkmul(sre[j], sre[j]));
            psum = pkadd(psum, p);
            if (j & 8)                        s0 = pkfma(p, MONE, s0); else s0 = pkadd(s0, p);
            if (j & 4)                        s1 = pkfma(p, MONE, s1); else s1 = pkadd(s1, p);
            if ((((j >> 1) ^ (j >> 2)) & 1))  s2 = pkfma(p, MONE, s2); else s2 = pkadd(s2, p);
            if (j & 1)                        s3 = pkfma(p, MONE, s3); else s3 = pkadd(s3, p);
        }
    }
    v2f vals[12];
    {
        int t = tid;
        int mt = t ^ ((t >> 1) & 0xAA);       // sigma on low 8 bits
        vals[0] = s0; vals[1] = s1; vals[2] = s2; vals[3] = s3;
        vals[4]  = ((t >> 7) & 1)  ? -s3 : s3;     // qubit4: bit7 = t7 ^ j0
        vals[5]  = ((mt >> 6) & 1) ? -psum : psum;
        vals[6]  = ((mt >> 5) & 1) ? -psum : psum;
        vals[7]  = ((mt >> 4) & 1) ? -psum : psum;
        vals[8]  = ((mt >> 3) & 1) ? -psum : psum;
        vals[9]  = ((mt >> 2) & 1) ? -psum : psum;
        vals[10] = ((mt >> 1) & 1) ? -psum : psum;
        vals[11] = (mt & 1)        ? -psum : psum;
    }
    const int lane = tid & 63, wv = tid >> 6;
    #pragma unroll
    for (int q = 0; q < 12; ++q) {
        v2f v = vals[q];
        #pragma unroll
        for (int mm = 32; mm >= 1; mm >>= 1) {
            v.x += __shfl_xor(v.x, mm, 64);
            v.y += __shfl_xor(v.y, mm, 64);
        }
        if (lane == 0) red[q * 4 + wv] = v;
    }
    __syncthreads();

    if (tid < 12) {
        v2f v = pkadd(pkadd(red[tid*4+0], red[tid*4+1]), pkadd(red[tid*4+2], red[tid*4+3]));
        float A0 = alpha[0], A1 = alpha[1], A2 = alpha[2], A3 = alpha[3];
        float mx = fmaxf(fmaxf(A0, A1), fmaxf(A2, A3));
        float E0 = expf(A0-mx), E1 = expf(A1-mx), E2 = expf(A2-mx), E3 = expf(A3-mx);
        float den = E0 + E1 + E2 + E3;
        if (special) {
            wez[tid] = (E2 / den) * v.x;
        } else {
            int eslA = gA % 3, bA = gA / 3;
            int eslB = gB % 3, bB = gB / 3;
            float wA = ((eslA == 0) ? E0 : (eslA == 1) ? E1 : E3) / den;
            float wB = ((eslB == 0) ? E0 : (eslB == 1) ? E1 : E3) / den;
            atomicAdd(out + bA * NQ + tid, wA * v.x);
            atomicAdd(out + bB * NQ + tid, wB * v.y);
        }
    }
    if (special) {
        __syncthreads();
        for (int bb2 = tid; bb2 < 1024; bb2 += THREADS) {
            #pragma unroll
            for (int q = 0; q < NQ; ++q)
                atomicAdd(out + bb2 * NQ + q, wez[q]);
        }
    }
}

extern "C" void kernel_launch(void* const* d_in, const int* in_sizes, int n_in,
                              void* d_out, int out_size, void* d_ws, size_t ws_size,
                              hipStream_t stream) {
    const float* features = (const float*)d_in[0];
    const float* theta    = (const float*)d_in[1];
    const float* alpha    = (const float*)d_in[2];
    float* out = (float*)d_out;

    hipMemsetAsync(out, 0, (size_t)out_size * sizeof(float), stream);
    // block 0 = shared h_angle_rx circuit; blocks 1..1536 = pairs of regular circuits
    vqc_kernel<<<dim3(1537), THREADS, 0, stream>>>(features, theta, alpha, out);
}

// Round 4
// 134.859 us; speedup vs baseline: 2.7360x; 1.0713x over previous
//
#include <hip/hip_runtime.h>
#include <math.h>

#define NQ 12
#define DIM 4096
#define NL 4
#define THREADS 256
#define SWZC(e) ((e) ^ (((e) >> 3) & 14) ^ (((e) >> 7) & 15))
#define WAVEFENCE() { __builtin_amdgcn_wave_barrier(); __builtin_amdgcn_sched_barrier(0); }

typedef float v2f __attribute__((ext_vector_type(2)));

__device__ __forceinline__ v2f pkfma(v2f a, v2f b, v2f c) {
    v2f d; asm("v_pk_fma_f32 %0, %1, %2, %3" : "=v"(d) : "v"(a), "v"(b), "v"(c)); return d;
}
__device__ __forceinline__ v2f pkmul(v2f a, v2f b) {
    v2f d; asm("v_pk_mul_f32 %0, %1, %2" : "=v"(d) : "v"(a), "v"(b)); return d;
}
__device__ __forceinline__ v2f pkadd(v2f a, v2f b) {
    v2f d; asm("v_pk_add_f32 %0, %1, %2" : "=v"(d) : "v"(a), "v"(b)); return d;
}
__device__ __forceinline__ float2 cmulS(float2 a, float2 b) {
    return make_float2(fmaf(a.x, b.x, -a.y * b.y), fmaf(a.x, b.y, a.y * b.x));
}

struct C4 { v2f r, i, ni, nr; };   // (re,re),(im,im),(-im,-im),(-re,-re)

// complex K*x with K given as component slots (R, NI = -Im, I = Im)
#define CMUL4(orE, orI, KR, KNI, KI, xre, xim) \
    { orE = pkfma(KNI, xim, pkmul(KR, xre)); orI = pkfma(KI, xre, pkmul(KR, xim)); }
#define CMAC4(orE, orI, KR, KNI, KI, xre, xim) \
    { orE = pkfma(KR, xre, pkfma(KNI, xim, orE)); orI = pkfma(KR, xim, pkfma(KI, xre, orI)); }

// SU(2) 2-stage 4x4 pair-gate; lo = [[a,b],[-b*,a*]] with a=la,b=lb; hi likewise.
// even-CNOT baked in: outputs C<-y3, D<-y2.
#define QUADBODY(A_, B_, C_, D_) { \
    v2f z0r,z0i,z1r,z1i,z2r,z2i,z3r,z3i; \
    CMUL4(z0r,z0i, la.r, la.ni, la.i, sre[A_], sim[A_]); CMAC4(z0r,z0i, lb.r, lb.ni, lb.i, sre[B_], sim[B_]); \
    CMUL4(z1r,z1i, lb.nr, lb.ni, lb.i, sre[A_], sim[A_]); CMAC4(z1r,z1i, la.r, la.i, la.ni, sre[B_], sim[B_]); \
    CMUL4(z2r,z2i, la.r, la.ni, la.i, sre[C_], sim[C_]); CMAC4(z2r,z2i, lb.r, lb.ni, lb.i, sre[D_], sim[D_]); \
    CMUL4(z3r,z3i, lb.nr, lb.ni, lb.i, sre[C_], sim[C_]); CMAC4(z3r,z3i, la.r, la.i, la.ni, sre[D_], sim[D_]); \
    v2f y0r,y0i,y1r,y1i,y2r,y2i,y3r,y3i; \
    CMUL4(y0r,y0i, ha.r, ha.ni, ha.i, z0r, z0i); CMAC4(y0r,y0i, hb.r, hb.ni, hb.i, z2r, z2i); \
    CMUL4(y1r,y1i, ha.r, ha.ni, ha.i, z1r, z1i); CMAC4(y1r,y1i, hb.r, hb.ni, hb.i, z3r, z3i); \
    CMUL4(y2r,y2i, hb.nr, hb.ni, hb.i, z0r, z0i); CMAC4(y2r,y2i, ha.r, ha.i, ha.ni, z2r, z2i); \
    CMUL4(y3r,y3i, hb.nr, hb.ni, hb.i, z1r, z1i); CMAC4(y3r,y3i, ha.r, ha.i, ha.ni, z3r, z3i); \
    sre[A_]=y0r; sim[A_]=y0i; sre[B_]=y1r; sim[B_]=y1i; \
    sre[C_]=y3r; sim[C_]=y3i; sre[D_]=y2r; sim[D_]=y2i; }

__device__ __forceinline__ void pass_hi(v2f* sre, v2f* sim, const v2f (*U)[4]) {
    C4 la={U[0][0],U[0][1],U[0][2],U[0][3]}, lb={U[1][0],U[1][1],U[1][2],U[1][3]},
       ha={U[2][0],U[2][1],U[2][2],U[2][3]}, hb={U[3][0],U[3][1],U[3][2],U[3][3]};
    QUADBODY(0,4,8,12) QUADBODY(1,5,9,13) QUADBODY(2,6,10,14) QUADBODY(3,7,11,15)
}
__device__ __forceinline__ void pass_lo(v2f* sre, v2f* sim, const v2f (*U)[4]) {
    C4 la={U[0][0],U[0][1],U[0][2],U[0][3]}, lb={U[1][0],U[1][1],U[1][2],U[1][3]},
       ha={U[2][0],U[2][1],U[2][2],U[2][3]}, hb={U[3][0],U[3][1],U[3][2],U[3][3]};
    QUADBODY(0,1,2,3) QUADBODY(4,5,6,7) QUADBODY(8,9,10,11) QUADBODY(12,13,14,15)
}

__global__ __launch_bounds__(THREADS, 4)
void vqc_kernel(const float* __restrict__ features,
                const float* __restrict__ theta,
                const float* __restrict__ alpha,
                float* __restrict__ out)
{
    __shared__ v2f scr[DIM];              // 32 KB relayout scratch (one plane at a time)
    __shared__ v2f Upk[24][4][4];         // 3 KB: per (layer,pair): la,lb,ha,hb x (r,i,ni,nr)
    __shared__ v2f red[12 * 4];
    __shared__ float wez[12];

    // build-phase tables aliased into scr (dead before first relayout)
    float2* cs = (float2*)scr;                                      // [0,1152)   144 f2
    float2 (*U48)[4] = (float2(*)[4])((char*)scr + 1152);           // [1152,2688) 48x4 f2
    float2 (*enc)[2] = (float2(*)[2])((char*)scr + 2688);           // [2688,3072) 24x2 f2
    float2 (*pairT)[4] = (float2(*)[4])((char*)scr + 3072);         // [3072,3456) 12x4 f2
    float2* loc = (float2*)((char*)scr + 3456);                     // [3456,3712) 32 f2

    const int tid = threadIdx.x;
    const bool special = (blockIdx.x == 0);   // shared h_angle_rx circuit (|+>^12 up to phase)
    const int gA = special ? 0 : 2 * ((int)blockIdx.x - 1);
    const int gB = gA + 1;

    // ---- stage 1: theta sincos + encoding states (2 circuits) ----
    if (tid < NL * NQ * 3) {
        float s, c; sincosf(0.5f * theta[tid], &s, &c);
        cs[tid] = make_float2(c, s);
    }
    if (tid >= 160 && tid < 184) {
        int c_ = (tid - 160) / 12, q = (tid - 160) % 12;
        const float r_ = 0.70710678118654752f;
        float2 a0, a1;
        if (special) { a0 = make_float2(r_, 0.f); a1 = a0; }
        else {
            int g = c_ ? gB : gA;
            int esl = g % 3, b = g / 3;
            float f = features[b * NQ + q];
            float s, c; sincosf(0.5f * f, &s, &c);
            if (esl == 0)      { a0 = make_float2(c, 0.f); a1 = make_float2(0.f, -s); }
            else if (esl == 1) { a0 = make_float2(c, 0.f); a1 = make_float2(s, 0.f); }
            else               { a0 = make_float2((c-s)*r_, 0.f); a1 = make_float2((c+s)*r_, 0.f); }
        }
        enc[c_ * NQ + q][0] = a0; enc[c_ * NQ + q][1] = a1;
    }
    __syncthreads();

    // ---- stage 2: fused U = RZ*RY*RX (only u00=a, u01=b needed; SU(2)) + pair tables ----
    if (tid < NL * NQ) {
        float c0 = cs[tid*3+0].x, s0 = cs[tid*3+0].y;
        float c1 = cs[tid*3+1].x, s1 = cs[tid*3+1].y;
        float c2 = cs[tid*3+2].x, s2 = cs[tid*3+2].y;
        float2 a00 = make_float2( c1*c0,  s1*s0);
        float2 a01 = make_float2(-s1*c0, -c1*s0);
        float2 a10 = make_float2( s1*c0, -c1*s0);
        float2 a11 = make_float2( c1*c0, -s1*s0);
        float2 ep = make_float2(c2, -s2), em = make_float2(c2, s2);
        U48[tid][0] = cmulS(ep, a00); U48[tid][1] = cmulS(ep, a01);
        U48[tid][2] = cmulS(em, a10); U48[tid][3] = cmulS(em, a11);
    }
    if (tid >= 64 && tid < 112) {
        int x = tid - 64;
        int c_ = x / 24, y = x % 24, p = y >> 2, v = y & 3;
        pairT[c_ * 6 + p][v] = cmulS(enc[c_*NQ + 2*p][v >> 1], enc[c_*NQ + 2*p + 1][v & 1]);
    }
    __syncthreads();

    // ---- stage 3: packed SU(2) coeff quads + local product table ----
    for (int idx = tid; idx < 384; idx += THREADS) {
        int p = idx >> 4, rest = idx & 15, c = rest >> 2, comp = rest & 3;
        int l = p / 6, m = p % 6;
        int q = (c < 2) ? (2*m + 1) : (2*m);       // c0,c1: lo qubit; c2,c3: hi qubit
        float2 u = U48[l*NQ + q][c & 1];           // col 0 = a(u00), col 1 = b(u01)
        float xv = (comp == 0) ? u.x : (comp == 1) ? u.y : (comp == 2) ? -u.y : -u.x;
        v2f vv = {xv, xv};
        Upk[p][c][comp] = vv;
    }
    if (tid >= 192 && tid < 224) {
        int x = tid - 192; int c_ = x >> 4, j = x & 15;
        loc[c_ * 16 + j] = cmulS(pairT[c_*6 + 4][j >> 2], pairT[c_*6 + 5][j & 3]);
    }
    __syncthreads();

    // ---- build product state into LA registers (i = tid<<4 | j) ----
    v2f sre[16], sim[16];
    {
        int t = tid;
        float2 preA = cmulS(cmulS(pairT[0][(t>>6)&3], pairT[1][(t>>4)&3]),
                            cmulS(pairT[2][(t>>2)&3], pairT[3][t&3]));
        float2 preB = cmulS(cmulS(pairT[6][(t>>6)&3], pairT[7][(t>>4)&3]),
                            cmulS(pairT[8][(t>>2)&3], pairT[9][t&3]));
        #pragma unroll
        for (int j = 0; j < 16; ++j) {
            float2 aA = cmulS(preA, loc[j]);
            float2 aB = cmulS(preB, loc[16 + j]);
            v2f r = {aA.x, aB.x}, ii = {aA.y, aB.y};
            sre[j] = r; sim[j] = ii;
        }
    }
    __syncthreads();   // tables (in scr) dead; all reads done before first relayout write

    // ---- 4 variational layers ----
    #pragma unroll 1
    for (int l = 0; l < NL; ++l) {
        // LA: pairs P4 (bits 3,2), P5 (bits 1,0)
        pass_hi(sre, sim, Upk[l*6 + 4]);
        pass_lo(sre, sim, Upk[l*6 + 5]);
        // relayout LA -> LB : wave-local (16-lane groups, SWZC preserves bits 11:10)
        {
            int ba = SWZC(tid << 4);
            int ib = ((tid >> 4) << 8) | (tid & 15);
            int bb = SWZC(ib);
            #pragma unroll
            for (int j = 0; j < 16; ++j) scr[ba ^ j] = sre[j];
            WAVEFENCE();
            #pragma unroll
            for (int j = 0; j < 16; ++j) sre[j] = scr[bb ^ SWZC(j << 4)];
            WAVEFENCE();
            #pragma unroll
            for (int j = 0; j < 16; ++j) scr[ba ^ j] = sim[j];
            WAVEFENCE();
            #pragma unroll
            for (int j = 0; j < 16; ++j) sim[j] = scr[bb ^ SWZC(j << 4)];
            WAVEFENCE();
        }
        // LB: pairs P2 (bits 7,6), P3 (bits 5,4)
        pass_hi(sre, sim, Upk[l*6 + 2]);
        pass_lo(sre, sim, Upk[l*6 + 3]);
        // relayout LB -> LC : cross-wave (reads pull other quarters), plane-chunked
        {
            int ib = ((tid >> 4) << 8) | (tid & 15);
            int bb = SWZC(ib);
            int bc = SWZC(tid);
            #pragma unroll
            for (int j = 0; j < 16; ++j) scr[bb ^ SWZC(j << 4)] = sre[j];
            __syncthreads();
            #pragma unroll
            for (int j = 0; j < 16; ++j) sre[j] = scr[bc ^ SWZC(j << 8)];
            __syncthreads();
            #pragma unroll
            for (int j = 0; j < 16; ++j) scr[bb ^ SWZC(j << 4)] = sim[j];
            __syncthreads();
            #pragma unroll
            for (int j = 0; j < 16; ++j) sim[j] = scr[bc ^ SWZC(j << 8)];
            __syncthreads();
        }
        // LC: pairs P0 (bits 11,10), P1 (bits 9,8)
        pass_hi(sre, sim, Upk[l*6 + 0]);
        pass_lo(sre, sim, Upk[l*6 + 1]);
        if (l < NL - 1) {
            // relayout LC -> LA with odd-CNOT sigma folded (writes cross, reads own-quarter)
            int bc = SWZC(tid);
            int t = tid;
            int sx = (t << 4) ^ ((t & 1) << 3) ^ (((t >> 2) & 1) << 5)
                             ^ (((t >> 4) & 1) << 7) ^ (((t >> 6) & 1) << 9);
            int bs = SWZC(sx);
            #pragma unroll
            for (int j = 0; j < 16; ++j) scr[bc ^ SWZC(j << 8)] = sre[j];
            __syncthreads();
            #pragma unroll
            for (int j = 0; j < 16; ++j) { int sj = j ^ ((j >> 1) & 2); sre[j] = scr[bs ^ sj]; }
            __syncthreads();
            #pragma unroll
            for (int j = 0; j < 16; ++j) scr[bc ^ SWZC(j << 8)] = sim[j];
            __syncthreads();
            #pragma unroll
            for (int j = 0; j < 16; ++j) { int sj = j ^ ((j >> 1) & 2); sim[j] = scr[bs ^ sj]; }
            WAVEFENCE();   // next scr write (wl LA->LB of l+1) is own-quarter: no block barrier needed
        }
    }

    // ---- measurement in LC, layer-3 sigma folded into sign indices ----
    v2f s0 = {0.f,0.f}, s1 = {0.f,0.f}, s2 = {0.f,0.f}, s3 = {0.f,0.f}, psum = {0.f,0.f};
    {
        const v2f MONE = {-1.f, -1.f};
        #pragma unroll
        for (int j = 0; j < 16; ++j) {
            v2f p = pkfma(sim[j], sim[j], pkmul(sre[j], sre[j]));
            psum = pkadd(psum, p);
            if (j & 8)                        s0 = pkfma(p, MONE, s0); else s0 = pkadd(s0, p);
            if (j & 4)                        s1 = pkfma(p, MONE, s1); else s1 = pkadd(s1, p);
            if ((((j >> 1) ^ (j >> 2)) & 1))  s2 = pkfma(p, MONE, s2); else s2 = pkadd(s2, p);
            if (j & 1)                        s3 = pkfma(p, MONE, s3); else s3 = pkadd(s3, p);
        }
    }
    v2f vals[12];
    {
        int t = tid;
        int mt = t ^ ((t >> 1) & 0xAA);
        vals[0] = s0; vals[1] = s1; vals[2] = s2; vals[3] = s3;
        vals[4]  = ((t >> 7) & 1)  ? -s3 : s3;
        vals[5]  = ((mt >> 6) & 1) ? -psum : psum;
        vals[6]  = ((mt >> 5) & 1) ? -psum : psum;
        vals[7]  = ((mt >> 4) & 1) ? -psum : psum;
        vals[8]  = ((mt >> 3) & 1) ? -psum : psum;
        vals[9]  = ((mt >> 2) & 1) ? -psum : psum;
        vals[10] = ((mt >> 1) & 1) ? -psum : psum;
        vals[11] = (mt & 1)        ? -psum : psum;
    }
    const int lane = tid & 63, wv = tid >> 6;
    #pragma unroll
    for (int q = 0; q < 12; ++q) {
        v2f v = vals[q];
        #pragma unroll
        for (int mm = 32; mm >= 1; mm >>= 1) {
            v.x += __shfl_xor(v.x, mm, 64);
            v.y += __shfl_xor(v.y, mm, 64);
        }
        if (lane == 0) red[q * 4 + wv] = v;
    }
    __syncthreads();

    if (tid < 12) {
        v2f v = pkadd(pkadd(red[tid*4+0], red[tid*4+1]), pkadd(red[tid*4+2], red[tid*4+3]));
        float A0 = alpha[0], A1 = alpha[1], A2 = alpha[2], A3 = alpha[3];
        float mx = fmaxf(fmaxf(A0, A1), fmaxf(A2, A3));
        float E0 = expf(A0-mx), E1 = expf(A1-mx), E2 = expf(A2-mx), E3 = expf(A3-mx);
        float den = E0 + E1 + E2 + E3;
        if (special) {
            wez[tid] = (E2 / den) * v.x;
        } else {
            int eslA = gA % 3, bA = gA / 3;
            int eslB = gB % 3, bB = gB / 3;
            float wA = ((eslA == 0) ? E0 : (eslA == 1) ? E1 : E3) / den;
            float wB = ((eslB == 0) ? E0 : (eslB == 1) ? E1 : E3) / den;
            atomicAdd(out + bA * NQ + tid, wA * v.x);
            atomicAdd(out + bB * NQ + tid, wB * v.y);
        }
    }
    if (special) {
        __syncthreads();
        for (int bb2 = tid; bb2 < 1024; bb2 += THREADS) {
            #pragma unroll
            for (int q = 0; q < NQ; ++q)
                atomicAdd(out + bb2 * NQ + q, wez[q]);
        }
    }
}

extern "C" void kernel_launch(void* const* d_in, const int* in_sizes, int n_in,
                              void* d_out, int out_size, void* d_ws, size_t ws_size,
                              hipStream_t stream) {
    const float* features = (const float*)d_in[0];
    const float* theta    = (const float*)d_in[1];
    const float* alpha    = (const float*)d_in[2];
    float* out = (float*)d_out;

    hipMemsetAsync(out, 0, (size_t)out_size * sizeof(float), stream);
    vqc_kernel<<<dim3(1537), THREADS, 0, stream>>>(features, theta, alpha, out);
}